// Round 2
// baseline (781.208 us; speedup 1.0000x reference)
//
#include <hip/hip_runtime.h>

#define HH 50
#define NB 8            // batch elements per block
#define TT 512
#define NTH 512
#define NT 13           // tiles of 4 units (52 >= 50)
#define AS 136          // shorts per activation row: 128 k-slots + 8 pad (272B; 17 16B-groups, odd -> conflict-free b128)
#define NFRAG (NT * 12)

typedef __attribute__((ext_vector_type(8))) short short8;
typedef __attribute__((ext_vector_type(4))) float f32x4;

#define MFMA(a, b, c) __builtin_amdgcn_mfma_f32_16x16x32_bf16((a), (b), (c), 0, 0, 0)

__device__ __forceinline__ unsigned short f2bf(float f) {
    unsigned int u = __float_as_uint(f);
    u += 0x7FFFu + ((u >> 16) & 1u);
    return (unsigned short)(u >> 16);
}
__device__ __forceinline__ float bf2f(unsigned short s) {
    return __uint_as_float(((unsigned int)s) << 16);
}
// clamp-free: saturates correctly through inf (rcp(inf)=0), no NaN for finite v
__device__ __forceinline__ float fsig(float v) {
    return __builtin_amdgcn_rcpf(1.f + __builtin_amdgcn_exp2f(v * -1.442695041f));
}
__device__ __forceinline__ float ftanh(float v) {
    return fmaf(-2.f, __builtin_amdgcn_rcpf(1.f + __builtin_amdgcn_exp2f(v * 2.885390082f)), 1.f);
}

// ---------------- prep kernel: gate-interleaved A-operand weight fragments ----------------
// Tile nt covers units 4nt..4nt+3; row-in-tile r: unit = 4nt + (r>>2), gate = r&3.
// Slot map per tile: 0..3 = L0 kt{0,1}x{hi,lo} (K = [Whh0(50)|Wih0(3)|bias1|0..]);
//                    4..11 = L1 kt{0..3}x{hi,lo} (K = [Wih1(50)|Whh1(50)|bias1|0..]).
__global__ void prep_frags(
    const float* __restrict__ W_ih0, const float* __restrict__ W_hh0,
    const float* __restrict__ b_ih0, const float* __restrict__ b_hh0,
    const float* __restrict__ W_ih1, const float* __restrict__ W_hh1,
    const float* __restrict__ b_ih1, const float* __restrict__ b_hh1,
    unsigned short* __restrict__ ws)
{
    const int idx = blockIdx.x * blockDim.x + threadIdx.x;
    if (idx >= NFRAG * 64) return;
    const int lane = idx & 63;
    const int fid  = idx >> 6;
    const int nt   = fid / 12;
    const int slot = fid - nt * 12;
    const int r    = lane & 15;
    const int q    = lane >> 4;
    const int u    = nt * 4 + (r >> 2);
    const int gi   = r & 3;
    const int n    = gi * HH + u;          // original weight row
    const int layer = (slot < 4) ? 0 : 1;
    const int s     = (slot < 4) ? slot : (slot - 4);
    const int kt    = s >> 1;
    const int ishi  = !(s & 1);

    short8 v;
    #pragma unroll
    for (int jj = 0; jj < 8; ++jj) {
        const int k = kt * 32 + q * 8 + jj;
        float w = 0.f;
        if (u < HH) {
            if (layer == 0) {
                if (k < 50)       w = W_hh0[n * 50 + k];
                else if (k < 53)  w = W_ih0[n * 3 + (k - 50)];
                else if (k == 53) w = b_ih0[n] + b_hh0[n];
            } else {
                if (k < 50)        w = W_ih1[n * 50 + k];
                else if (k < 100)  w = W_hh1[n * 50 + (k - 50)];
                else if (k == 100) w = b_ih1[n] + b_hh1[n];
            }
        }
        const unsigned short h = f2bf(w);
        v[jj] = (short)(ishi ? h : f2bf(w - bf2f(h)));
    }
    *(short8*)&ws[((size_t)fid * 64 + lane) * 8] = v;
}

// ---------------- main kernel: decoupled L0/L1 tasks, balanced waves, split chains ----------------
// Task assignment (234 MFMA total, max 30/wave):
//   waves 0-5: L0 tile {w}        + L1 tiles {2w, 2w+1}   -> 6 + 24 = 30 MFMA
//   wave 6:    L0 tiles {6,7,8}   + L1 tile {12}          -> 18 + 12 = 30 MFMA
//   wave 7:    L0 tiles {9..12}   + x-writer              -> 24 MFMA
// Zero-skip reads: kt2-3 masked to col>=8 (rows 0-7 zero there); wave 7 reads kt0-1
// masked to col<8 (its cols 8-15 outputs unused). 64 -> 44 KB LDS read per step.
__global__ __launch_bounds__(NTH, 2) void lstm_mfma_v9(
    const float* __restrict__ x,
    const unsigned short* __restrict__ ws,
    const float* __restrict__ fc_w, const float* __restrict__ fc_b,
    float* __restrict__ out)
{
    __shared__ __align__(16) unsigned short Ahi[2][16 * AS];
    __shared__ __align__(16) unsigned short Alo[2][16 * AS];
    __shared__ float hBf[NB * 52];

    const int tid  = threadIdx.x;
    const int lane = tid & 63;
    const int wid  = tid >> 6;
    const int col  = lane & 15;
    const int q4   = lane >> 4;
    const int b0   = blockIdx.x * NB;

    for (int i = tid; i < 16 * AS; i += NTH) {
        Ahi[0][i] = 0; Alo[0][i] = 0; Ahi[1][i] = 0; Alo[1][i] = 0;
    }
    __syncthreads();
    if (tid < NB) {                                   // bias columns, both buffers
        Ahi[0][tid * AS + 53] = 0x3F80;        Ahi[1][tid * AS + 53] = 0x3F80;
        Ahi[0][(tid + 8) * AS + 100] = 0x3F80; Ahi[1][(tid + 8) * AS + 100] = 0x3F80;
    }

    // ---- slot -> tile maps (wave-uniform) ----
    const int l0nt0 = (wid < 6) ? wid : ((wid == 6) ? 6 : 9);
    const int l0nt1 = (wid == 6) ? 7 : 10;
    const int l0nt2 = (wid == 6) ? 8 : 11;
    const int l0nt3 = 12;
    const bool l0v1 = (wid >= 6), l0v2 = (wid >= 6), l0v3 = (wid == 7);
    const int l1nt0 = (wid < 6) ? (2 * wid) : 12;
    const int l1nt1 = 2 * wid + 1;
    const bool l1v0 = (wid < 7), l1v1 = (wid < 6);

    // ---- weight fragments (registers; zero for unused slots) ----
    const short8* wsf = (const short8*)ws;
    const short8 z8 = {0, 0, 0, 0, 0, 0, 0, 0};
    short8 w0h[4][2], w0l[4][2], w1h[2][4], w1l[2][4];
    {
        const int   nts[4] = {l0nt0, l0nt1, l0nt2, l0nt3};
        const bool  vs[4]  = {true, l0v1, l0v2, l0v3};
        #pragma unroll
        for (int s = 0; s < 4; ++s) {
            const size_t gb = (size_t)(vs[s] ? nts[s] : 0) * (12 * 64) + lane;
            #pragma unroll
            for (int kt = 0; kt < 2; ++kt) {
                w0h[s][kt] = vs[s] ? wsf[gb + (size_t)(kt * 2 + 0) * 64] : z8;
                w0l[s][kt] = vs[s] ? wsf[gb + (size_t)(kt * 2 + 1) * 64] : z8;
            }
        }
        const int   nts1[2] = {l1nt0, l1nt1};
        const bool  vs1[2]  = {l1v0, l1v1};
        #pragma unroll
        for (int s = 0; s < 2; ++s) {
            const size_t gb = (size_t)(vs1[s] ? nts1[s] : 0) * (12 * 64) + lane;
            #pragma unroll
            for (int kt = 0; kt < 4; ++kt) {
                w1h[s][kt] = vs1[s] ? wsf[gb + (size_t)(4 + kt * 2 + 0) * 64] : z8;
                w1l[s][kt] = vs1[s] ? wsf[gb + (size_t)(4 + kt * 2 + 1) * 64] : z8;
            }
        }
    }

    // ---- per-slot write offsets & per-lane guards (loop-invariant) ----
    const int u00 = l0nt0 * 4 + q4, u01 = l0nt1 * 4 + q4;
    const int u02 = l0nt2 * 4 + q4, u03 = l0nt3 * 4 + q4;
    const int u10 = l1nt0 * 4 + q4, u11 = l1nt1 * 4 + q4;
    const bool g00 = (col < 8) && (u00 < HH);
    const bool g01 = l0v1 && (col < 8) && (u01 < HH);
    const bool g02 = l0v2 && (col < 8) && (u02 < HH);
    const bool g03 = l0v3 && (col < 8) && (u03 < HH);
    const bool g10 = l1v0 && (col >= 8) && (u10 < HH);
    const bool g11 = l1v1 && (col >= 8) && (u11 < HH);
    const int o00 = col * AS + u00, o01 = col * AS + u01;
    const int o02 = col * AS + u02, o03 = col * AS + u03;
    const int o10 = col * AS + 50 + u10, o11 = col * AS + 50 + u11;
    const int hb10 = (col - 8) * 52 + u10, hb11 = (col - 8) * 52 + u11;

    float c00 = 0.f, c01 = 0.f, c02 = 0.f, c03 = 0.f;  // L0 cell states per slot
    float c10 = 0.f, c11 = 0.f;                        // L1 cell states per slot

    // ---- x-writer role: wave 7 lanes 0..23 ----
    float xv = 0.f; size_t xbase = 0; int xb = 0, xc = 0;
    const bool isx = (tid >= 448 && tid < 448 + NB * 3);
    if (isx) {
        const int i = tid - 448;
        xb = i / 3; xc = i - xb * 3;
        xbase = (size_t)(b0 + xb) * (TT * 3);
        const float x0 = x[xbase + xc];               // t = 0
        const unsigned short h = f2bf(x0);
        Ahi[0][xb * AS + 50 + xc] = h;
        Alo[0][xb * AS + 50 + xc] = f2bf(x0 - bf2f(h));
        xv = x[xbase + 3 + xc];                       // prefetch t = 1
    }
    __syncthreads();

    const int rbase = col * AS + q4 * 8;

    // cell + dual-row store (L0: rows col and col+8)
    #define L0_TASK(WH, WL, CST, GUARD, OFF)                                          \
    {                                                                                 \
        f32x4 d1 = {0.f,0.f,0.f,0.f}, d2 = {0.f,0.f,0.f,0.f}, d3 = {0.f,0.f,0.f,0.f};\
        d1 = MFMA(WH[0], ah0, d1); d1 = MFMA(WH[1], ah1, d1);                         \
        d2 = MFMA(WL[0], ah0, d2); d2 = MFMA(WL[1], ah1, d2);                         \
        d3 = MFMA(WH[0], al0, d3); d3 = MFMA(WH[1], al1, d3);                         \
        const f32x4 a0v = (d1 + d2) + d3;                                             \
        if (tlo && GUARD) {                                                           \
            const float ii = fsig(a0v[0]), ff = fsig(a0v[1]);                         \
            const float gg = ftanh(a0v[2]), oo = fsig(a0v[3]);                        \
            CST = ff * CST + ii * gg;                                                 \
            const float h = oo * ftanh(CST);                                          \
            const unsigned short hh = f2bf(h), hl = f2bf(h - bf2f(hh));               \
            dhi[OFF] = hh;            dlo[OFF] = hl;                                  \
            dhi[OFF + 8 * AS] = hh;   dlo[OFF + 8 * AS] = hl;                         \
        }                                                                             \
    }

    #define L1_TASK(WH, WL, CST, GUARD, OFF, HBO)                                     \
    {                                                                                 \
        f32x4 e1 = {0.f,0.f,0.f,0.f}, e2 = {0.f,0.f,0.f,0.f}, e3 = {0.f,0.f,0.f,0.f};\
        e1 = MFMA(WH[0], ah0, e1); e1 = MFMA(WH[1], ah1, e1);                         \
        e1 = MFMA(WH[2], ah2, e1); e1 = MFMA(WH[3], ah3, e1);                         \
        e2 = MFMA(WL[0], ah0, e2); e2 = MFMA(WL[1], ah1, e2);                         \
        e2 = MFMA(WL[2], ah2, e2); e2 = MFMA(WL[3], ah3, e2);                         \
        e3 = MFMA(WH[0], al0, e3); e3 = MFMA(WH[1], al1, e3);                         \
        e3 = MFMA(WH[2], al2, e3); e3 = MFMA(WH[3], al3, e3);                         \
        const f32x4 a1v = (e1 + e2) + e3;                                             \
        if (thi && GUARD) {                                                           \
            const float ii = fsig(a1v[0]), ff = fsig(a1v[1]);                         \
            const float gg = ftanh(a1v[2]), oo = fsig(a1v[3]);                        \
            CST = ff * CST + ii * gg;                                                 \
            const float h = oo * ftanh(CST);                                          \
            const unsigned short hh = f2bf(h), hl = f2bf(h - bf2f(hh));               \
            dhi[OFF] = hh;            dlo[OFF] = hl;                                  \
            if (t == TT) hBf[HBO] = h;                                                \
        }                                                                             \
    }

    // ======== main loop: 1 barrier/step, double-buffered acts ========
    for (int t = 0; t <= TT; ++t) {
        const int p = t & 1;
        const unsigned short* shi = Ahi[p];
        const unsigned short* slo = Alo[p];
        unsigned short* dhi = Ahi[p ^ 1];
        unsigned short* dlo = Alo[p ^ 1];
        const bool tlo = (t < TT);       // L0 tasks active
        const bool thi = (t > 0);        // L1 tasks active

        short8 ah0, ah1, ah2, ah3, al0, al1, al2, al3;
        if (wid < 7) {
            ah0 = *(const short8*)&shi[rbase];       al0 = *(const short8*)&slo[rbase];
            ah1 = *(const short8*)&shi[rbase + 32];  al1 = *(const short8*)&slo[rbase + 32];
            if (col >= 8) {                          // rows 0-7 are exact zeros at k>=64
                ah2 = *(const short8*)&shi[rbase + 64];  al2 = *(const short8*)&slo[rbase + 64];
                ah3 = *(const short8*)&shi[rbase + 96];  al3 = *(const short8*)&slo[rbase + 96];
            } else { ah2 = z8; al2 = z8; ah3 = z8; al3 = z8; }
        } else {
            if (col < 8) {                           // L0-only wave: cols 8-15 outputs unused
                ah0 = *(const short8*)&shi[rbase];       al0 = *(const short8*)&slo[rbase];
                ah1 = *(const short8*)&shi[rbase + 32];  al1 = *(const short8*)&slo[rbase + 32];
            } else { ah0 = z8; al0 = z8; ah1 = z8; al1 = z8; }
            ah2 = z8; al2 = z8; ah3 = z8; al3 = z8;
        }

        L0_TASK(w0h[0], w0l[0], c00, g00, o00);              // all waves
        if (wid >= 6) {
            L0_TASK(w0h[1], w0l[1], c01, g01, o01);
            L0_TASK(w0h[2], w0l[2], c02, g02, o02);
        }
        if (wid == 7) {
            L0_TASK(w0h[3], w0l[3], c03, g03, o03);
        }
        if (wid < 7) {
            L1_TASK(w1h[0], w1l[0], c10, g10, o10, hb10);
        }
        if (wid < 6) {
            L1_TASK(w1h[1], w1l[1], c11, g11, o11, hb11);
        }

        if (isx) {                                    // stage x(t+1) for next iter
            const unsigned short h = f2bf(xv);
            dhi[xb * AS + 50 + xc] = h;
            dlo[xb * AS + 50 + xc] = f2bf(xv - bf2f(h));
            const int tn = (t + 2 < TT) ? (t + 2) : (TT - 1);
            xv = x[xbase + tn * 3 + xc];
        }
        __syncthreads();
    }

    // ======== final FC ========
    if (tid < NB * 3) {
        const int bb = tid / 3, o = tid - bb * 3;
        float a = fc_b[o];
        #pragma unroll
        for (int uu = 0; uu < HH; ++uu)
            a += hBf[bb * 52 + uu] * fc_w[o * HH + uu];
        out[(size_t)(b0 + bb) * 3 + o] = a;
    }
}

extern "C" void kernel_launch(void* const* d_in, const int* in_sizes, int n_in,
                              void* d_out, int out_size, void* d_ws, size_t ws_size,
                              hipStream_t stream) {
    const float* x     = (const float*)d_in[0];
    const float* W_ih0 = (const float*)d_in[1];
    const float* W_hh0 = (const float*)d_in[2];
    const float* b_ih0 = (const float*)d_in[3];
    const float* b_hh0 = (const float*)d_in[4];
    const float* W_ih1 = (const float*)d_in[5];
    const float* W_hh1 = (const float*)d_in[6];
    const float* b_ih1 = (const float*)d_in[7];
    const float* b_hh1 = (const float*)d_in[8];
    const float* fc_w  = (const float*)d_in[9];
    const float* fc_b  = (const float*)d_in[10];
    float* out = (float*)d_out;
    unsigned short* ws = (unsigned short*)d_ws;       // NFRAG*64*16 B = 156 KB

    const int prepN = NFRAG * 64;
    prep_frags<<<(prepN + 255) / 256, 256, 0, stream>>>(
        W_ih0, W_hh0, b_ih0, b_hh0, W_ih1, W_hh1, b_ih1, b_hh1, ws);

    const int B = 2048;
    dim3 grid(B / NB), block(NTH);
    lstm_mfma_v9<<<grid, block, 0, stream>>>(x, ws, fc_w, fc_b, out);
}

// Round 3
// 567.296 us; speedup vs baseline: 1.3771x; 1.3771x over previous
//
#include <hip/hip_runtime.h>

#define HH 50
#define NB 8            // batch elements per block
#define TT 512
#define NTH 512
#define NT 13           // tiles of 4 units (52 >= 50)
#define AS 136          // shorts per activation row: 128 k-slots + 8 pad (272B; odd 16B-groups -> 2-way-max bank alias)
#define XS (TT * 3 + 4) // x-stash row stride (words): 1540 -> batch rows offset by 4 banks each
#define NFRAG (NT * 12)

typedef __attribute__((ext_vector_type(8))) short short8;
typedef __attribute__((ext_vector_type(4))) float f32x4;

#define MFMA(a, b, c) __builtin_amdgcn_mfma_f32_16x16x32_bf16((a), (b), (c), 0, 0, 0)

__device__ __forceinline__ unsigned short f2bf(float f) {
    unsigned int u = __float_as_uint(f);
    u += 0x7FFFu + ((u >> 16) & 1u);
    return (unsigned short)(u >> 16);
}
__device__ __forceinline__ float bf2f(unsigned short s) {
    return __uint_as_float(((unsigned int)s) << 16);
}
// clamp-free: saturates correctly through inf (rcp(inf)=0), no NaN for finite v
__device__ __forceinline__ float fsig(float v) {
    return __builtin_amdgcn_rcpf(1.f + __builtin_amdgcn_exp2f(v * -1.442695041f));
}
__device__ __forceinline__ float ftanh(float v) {
    return fmaf(-2.f, __builtin_amdgcn_rcpf(1.f + __builtin_amdgcn_exp2f(v * 2.885390082f)), 1.f);
}

// ---------------- prep kernel: gate-interleaved A-operand weight fragments ----------------
// Tile nt covers units 4nt..4nt+3; row-in-tile r: unit = 4nt + (r>>2), gate = r&3.
// Slot map per tile: 0..3 = L0 kt{0,1}x{hi,lo} (K = [Whh0(50)|Wih0(3)|bias1|0..]);
//                    4..11 = L1 kt{0..3}x{hi,lo} (K = [Wih1(50)|Whh1(50)|bias1|0..]).
__global__ void prep_frags(
    const float* __restrict__ W_ih0, const float* __restrict__ W_hh0,
    const float* __restrict__ b_ih0, const float* __restrict__ b_hh0,
    const float* __restrict__ W_ih1, const float* __restrict__ W_hh1,
    const float* __restrict__ b_ih1, const float* __restrict__ b_hh1,
    unsigned short* __restrict__ ws)
{
    const int idx = blockIdx.x * blockDim.x + threadIdx.x;
    if (idx >= NFRAG * 64) return;
    const int lane = idx & 63;
    const int fid  = idx >> 6;
    const int nt   = fid / 12;
    const int slot = fid - nt * 12;
    const int r    = lane & 15;
    const int q    = lane >> 4;
    const int u    = nt * 4 + (r >> 2);
    const int gi   = r & 3;
    const int n    = gi * HH + u;          // original weight row
    const int layer = (slot < 4) ? 0 : 1;
    const int s     = (slot < 4) ? slot : (slot - 4);
    const int kt    = s >> 1;
    const int ishi  = !(s & 1);

    short8 v;
    #pragma unroll
    for (int jj = 0; jj < 8; ++jj) {
        const int k = kt * 32 + q * 8 + jj;
        float w = 0.f;
        if (u < HH) {
            if (layer == 0) {
                if (k < 50)       w = W_hh0[n * 50 + k];
                else if (k < 53)  w = W_ih0[n * 3 + (k - 50)];
                else if (k == 53) w = b_ih0[n] + b_hh0[n];
            } else {
                if (k < 50)        w = W_ih1[n * 50 + k];
                else if (k < 100)  w = W_hh1[n * 50 + (k - 50)];
                else if (k == 100) w = b_ih1[n] + b_hh1[n];
            }
        }
        const unsigned short h = f2bf(w);
        v[jj] = (short)(ishi ? h : f2bf(w - bf2f(h)));
    }
    *(short8*)&ws[((size_t)fid * 64 + lane) * 8] = v;
}

// ---------------- fused tile step: MFMA -> in-register cell -> h writeback ----------------
// (verbatim v8 structure: unified cell, all 16 cols useful, no masked loads)
__device__ __forceinline__ void tile_step(
    const int nt, const int t,
    const short8* ah, const short8* al,
    const short8 w0h[2], const short8 w0l[2],
    const short8 w1h[4], const short8 w1l[4],
    float& cst, const int col, const int q4,
    unsigned short* dhi, unsigned short* dlo, float* hBf)
{
    f32x4 a0 = {0.f, 0.f, 0.f, 0.f}, a1 = {0.f, 0.f, 0.f, 0.f};
    #pragma unroll
    for (int kt = 0; kt < 2; ++kt) {                 // layer0 gates (K = 64)
        a0 = MFMA(w0h[kt], ah[kt], a0);
        a0 = MFMA(w0l[kt], ah[kt], a0);
        a0 = MFMA(w0h[kt], al[kt], a0);
    }
    #pragma unroll
    for (int kt = 0; kt < 4; ++kt) {                 // layer1 gates (K = 128)
        a1 = MFMA(w1h[kt], ah[kt], a1);
        a1 = MFMA(w1l[kt], ah[kt], a1);
        a1 = MFMA(w1h[kt], al[kt], a1);
    }
    const bool isL0 = (col < 8);
    const bool run = isL0 ? (t < TT) : (t > 0);      // uniform true for 0<t<TT
    if (run) {
        const float g0 = isL0 ? a0[0] : a1[0];
        const float g1 = isL0 ? a0[1] : a1[1];
        const float g2 = isL0 ? a0[2] : a1[2];
        const float g3 = isL0 ? a0[3] : a1[3];
        const float ii = fsig(g0), ff = fsig(g1);
        const float gg = ftanh(g2), oo = fsig(g3);
        const float c = ff * cst + ii * gg;
        cst = c;
        const float h = oo * ftanh(c);
        const int u = nt * 4 + q4;
        if (u < HH) {
            const unsigned short hh = f2bf(h);
            const unsigned short hl = f2bf(h - bf2f(hh));
            if (isL0) {
                dhi[col * AS + u] = hh;            dlo[col * AS + u] = hl;        // L0 recurrent
                dhi[(col + 8) * AS + u] = hh;      dlo[(col + 8) * AS + u] = hl;  // L1 input
            } else {
                dhi[col * AS + 50 + u] = hh;       dlo[col * AS + 50 + u] = hl;   // L1 recurrent
                if (t == TT) hBf[(col - 8) * 52 + u] = h;
            }
        }
    }
}

// ---------------- main kernel: v8 + LDS x-stash (no vmem ops inside the barrier loop) ----------------
// v8's hidden stall: the x-writer's global load sat right before __syncthreads(), whose
// vmcnt(0) drain made all 8 waves eat L2/HBM latency EVERY step. x is now preloaded to an
// LDS stash (pre-split bf16 hi|lo packed in one word) before the loop.
__global__ __launch_bounds__(NTH, 2) void lstm_mfma_v10(
    const float* __restrict__ x,
    const unsigned short* __restrict__ ws,
    const float* __restrict__ fc_w, const float* __restrict__ fc_b,
    float* __restrict__ out)
{
    __shared__ __align__(16) unsigned short Ahi[2][16 * AS];
    __shared__ __align__(16) unsigned short Alo[2][16 * AS];
    __shared__ float hBf[NB * 52];
    __shared__ unsigned int xstash[NB * XS];          // 8 x 1540 words = 49.3 KB

    const int tid  = threadIdx.x;
    const int lane = tid & 63;
    const int wid  = tid >> 6;
    const int col  = lane & 15;
    const int q4   = lane >> 4;
    const int b0   = blockIdx.x * NB;

    for (int i = tid; i < 16 * AS; i += NTH) {
        Ahi[0][i] = 0; Alo[0][i] = 0; Ahi[1][i] = 0; Alo[1][i] = 0;
    }

    // ---- preload + pre-split the block's x slab (contiguous 48 KB) ----
    {
        const float* xg = x + (size_t)b0 * (TT * 3);
        for (int i = tid; i < (NB * TT * 3) / 4; i += NTH) {   // 3072 float4s, 6 iters
            const float4 v4 = ((const float4*)xg)[i];
            const int e = i * 4;
            #pragma unroll
            for (int j = 0; j < 4; ++j) {
                const float v = (&v4.x)[j];
                const int b = (e + j) / (TT * 3);
                const int r = (e + j) - b * (TT * 3);
                const unsigned short h = f2bf(v);
                const unsigned short l = f2bf(v - bf2f(h));
                xstash[b * XS + r] = (unsigned int)h | ((unsigned int)l << 16);
            }
        }
    }
    __syncthreads();

    if (tid < NB) {                                   // bias columns, both buffers
        Ahi[0][tid * AS + 53] = 0x3F80;        Ahi[1][tid * AS + 53] = 0x3F80;
        Ahi[0][(tid + 8) * AS + 100] = 0x3F80; Ahi[1][(tid + 8) * AS + 100] = 0x3F80;
    }

    // ---- weight fragments: wave w owns tile w, plus tile 8+w if w<5 ----
    const short8* wsf = (const short8*)ws;
    short8 w0h[2][2], w0l[2][2], w1h[2][4], w1l[2][4];
    const bool has2 = (wid < 5);
    #pragma unroll
    for (int i = 0; i < 2; ++i) {
        const int nt = (i == 0) ? wid : 8 + wid;
        const bool v = (i == 0) || has2;
        const size_t gb = (size_t)(v ? nt : 0) * (12 * 64) + lane;
        #pragma unroll
        for (int kt = 0; kt < 2; ++kt) {
            w0h[i][kt] = v ? wsf[gb + (size_t)(kt * 2 + 0) * 64] : short8{};
            w0l[i][kt] = v ? wsf[gb + (size_t)(kt * 2 + 1) * 64] : short8{};
        }
        #pragma unroll
        for (int kt = 0; kt < 4; ++kt) {
            w1h[i][kt] = v ? wsf[gb + (size_t)(4 + kt * 2 + 0) * 64] : short8{};
            w1l[i][kt] = v ? wsf[gb + (size_t)(4 + kt * 2 + 1) * 64] : short8{};
        }
    }

    // ---- x-writer role: wave 7 lanes 0..23 (1-tile wave) ----
    int xb = 0, xc = 0, xoff = 0;
    const bool isx = (tid >= 448 && tid < 448 + NB * 3);
    if (isx) {
        const int i = tid - 448;
        xb = i / 3; xc = i - xb * 3;
        xoff = xb * AS + 50 + xc;
        const unsigned int w0 = xstash[xb * XS + xc];          // x(0) -> buf 0
        Ahi[0][xoff] = (unsigned short)(w0 & 0xFFFFu);
        Alo[0][xoff] = (unsigned short)(w0 >> 16);
    }
    float cst0 = 0.f, cst1 = 0.f;                     // c-state per owned tile
    __syncthreads();

    // ======== single-phase main loop: read buf p, write buf p^1, ONE barrier ========
    for (int t = 0; t <= TT; ++t) {
        const int p = t & 1;
        unsigned short* shi = Ahi[p];
        unsigned short* slo = Alo[p];
        unsigned short* dhi = Ahi[p ^ 1];
        unsigned short* dlo = Alo[p ^ 1];

        short8 ah[4], al[4];                          // B-operand activation frags
        #pragma unroll
        for (int kt = 0; kt < 4; ++kt) {
            ah[kt] = *(const short8*)&shi[col * AS + kt * 32 + q4 * 8];
            al[kt] = *(const short8*)&slo[col * AS + kt * 32 + q4 * 8];
        }

        tile_step(wid, t, ah, al, w0h[0], w0l[0], w1h[0], w1l[0], cst0, col, q4, dhi, dlo, hBf);
        if (has2)
            tile_step(8 + wid, t, ah, al, w0h[1], w0l[1], w1h[1], w1l[1], cst1, col, q4, dhi, dlo, hBf);

        if (isx) {                                    // stage x(t+1) from LDS stash (no vmem!)
            const int tn1 = (t + 1 < TT) ? (t + 1) : (TT - 1);
            const unsigned int wrd = xstash[xb * XS + tn1 * 3 + xc];
            dhi[xoff] = (unsigned short)(wrd & 0xFFFFu);
            dlo[xoff] = (unsigned short)(wrd >> 16);
        }
        __syncthreads();
    }

    // ======== final FC ========
    if (tid < NB * 3) {
        const int bb = tid / 3, o = tid - bb * 3;
        float a = fc_b[o];
        #pragma unroll
        for (int uu = 0; uu < HH; ++uu)
            a += hBf[bb * 52 + uu] * fc_w[o * HH + uu];
        out[(size_t)(b0 + bb) * 3 + o] = a;
    }
}

extern "C" void kernel_launch(void* const* d_in, const int* in_sizes, int n_in,
                              void* d_out, int out_size, void* d_ws, size_t ws_size,
                              hipStream_t stream) {
    const float* x     = (const float*)d_in[0];
    const float* W_ih0 = (const float*)d_in[1];
    const float* W_hh0 = (const float*)d_in[2];
    const float* b_ih0 = (const float*)d_in[3];
    const float* b_hh0 = (const float*)d_in[4];
    const float* W_ih1 = (const float*)d_in[5];
    const float* W_hh1 = (const float*)d_in[6];
    const float* b_ih1 = (const float*)d_in[7];
    const float* b_hh1 = (const float*)d_in[8];
    const float* fc_w  = (const float*)d_in[9];
    const float* fc_b  = (const float*)d_in[10];
    float* out = (float*)d_out;
    unsigned short* ws = (unsigned short*)d_ws;       // NFRAG*64*16 B = 156 KB

    const int prepN = NFRAG * 64;
    prep_frags<<<(prepN + 255) / 256, 256, 0, stream>>>(
        W_ih0, W_hh0, b_ih0, b_hh0, W_ih1, W_hh1, b_ih1, b_hh1, ws);

    const int B = 2048;
    dim3 grid(B / NB), block(NTH);
    lstm_mfma_v10<<<grid, block, 0, stream>>>(x, ws, fc_w, fc_b, out);
}